// Round 1
// 186.888 us; speedup vs baseline: 1.0042x; 1.0042x over previous
//
#include <hip/hip_runtime.h>
#include <hip/hip_bf16.h>

constexpr int B_ = 4;
constexpr int L_ = 2048;
constexpr int D_ = 256;
constexpr int P_ = 32;
constexpr int CL = 32;   // chunk length for KV scan
constexpr int NC = L_ / CL;  // 64 chunks

#define PI_F 3.14159265358979323846f
#define INV_SQRT_P 0.17677669529663687f  // 1/sqrt(32)

typedef __attribute__((ext_vector_type(8))) short short8_t;
typedef __attribute__((ext_vector_type(4))) float floatx4;

static __device__ inline short f2bf(float f) {
  unsigned int u;
  __builtin_memcpy(&u, &f, 4);
  unsigned int r = (u + 0x7fffu + ((u >> 16) & 1u)) >> 16;
  return (short)r;
}
static __device__ inline float bf2f(short s) {
  unsigned int u = ((unsigned int)(unsigned short)s) << 16;
  float f;
  __builtin_memcpy(&f, &u, 4);
  return f;
}

// ---------------- wprep: weight casts/transposes + x->bf16 + poff + ctxsum -
__global__ void wprep(const float* __restrict__ x, const float* __restrict__ pos,
                      const float* __restrict__ w_val, const float* __restrict__ w_mem1v,
                      const float* __restrict__ w_off, const float* __restrict__ b_off,
                      const float* __restrict__ w_key, const float* __restrict__ w_gate,
                      const float* __restrict__ w_sk1, const float* __restrict__ w_out,
                      const float* __restrict__ w_sk2, const float* __restrict__ w_mem1o,
                      short* __restrict__ WA, short* __restrict__ W1,
                      short* __restrict__ WO, short* __restrict__ W2T,
                      short* __restrict__ W1OT,
                      short* __restrict__ xbf, float* __restrict__ poff,
                      float* __restrict__ ctxsum) {
  int blk = blockIdx.x, tid = threadIdx.x;
  if (blk < 384) {
    int idx = blk * 256 + tid;
    int n = idx >> 8, k = idx & 255;
    float v;
    if (n < 256) v = w_val[k * 256 + n];
    else if (n < 288) v = w_mem1v[k * 32 + (n - 256)];
    else if (n < 320) v = w_off[k * 32 + (n - 288)];
    else if (n < 352) v = w_key[k * 32 + (n - 320)];
    else if (n == 352) v = w_gate[k];
    else v = 0.f;
    WA[idx] = f2bf(v);
  } else if (blk < 896) {
    int idx = (blk - 384) * 256 + tid;
    int n = idx >> 9, k = idx & 511;
    W1[idx] = f2bf(w_sk1[k * 256 + n]);
  } else if (blk < 1152) {
    int idx = (blk - 896) * 256 + tid;
    int n = idx >> 8, k = idx & 255;
    WO[idx] = f2bf(w_out[k * 256 + n]);
  } else if (blk < 1184) {
    int idx = (blk - 1152) * 256 + tid;  // p*256 + k
    int p = idx >> 8, k = idx & 255;
    W2T[idx] = f2bf(w_sk2[k * 32 + p]);
  } else if (blk < 1216) {
    int idx = (blk - 1184) * 256 + tid;  // d*32 + p
    int d = idx >> 5, p = idx & 31;
    W1OT[idx] = f2bf(w_mem1o[p * 256 + d]);
  } else if (blk < 3264) {
    int idx = ((blk - 1216) * 256 + tid) * 4;
    float4 v = *(const float4*)&x[idx];
    short4 o;
    o.x = f2bf(v.x); o.y = f2bf(v.y); o.z = f2bf(v.z); o.w = f2bf(v.w);
    *(short4*)&xbf[idx] = o;
  } else if (blk < 3520) {
    int idx = (blk - 3264) * 256 + tid;
    int l = idx >> 5, p = idx & 31;
    float a = b_off[p];
    for (int j = 0; j < 32; ++j) a += pos[l * 32 + j] * w_off[(256 + j) * 32 + p];
    poff[idx] = a;
  } else {
    // ctx chunk sums: depends only on x
    int c2 = blk - 3520;
    int b = c2 >> 6, ch = c2 & 63;
    int xb = (b * L_ + ch * 32) * 256 + tid;
    float s = 0.f;
#pragma unroll 8
    for (int i = 0; i < 32; ++i) s += x[xb + i * 256];
    ctxsum[c2 * 256 + tid] = s;
  }
}

// ---------------- generic bf16 MFMA GEMM, 64x64 tile -----------------------
// MODE 1: hs bf16 = gelu(A @ W + bias)
// MODE 2: out fp32 = xres + A0 @ W + bias
template <int KTILES, int NBLK, int MODE>
__global__ __launch_bounds__(256) void gemm_k(const short* __restrict__ A0,
                                              const short* __restrict__ A1,
                                              const short* __restrict__ W,
                                              const float* __restrict__ bias,
                                              const float* __restrict__ xres,
                                              float* __restrict__ outf,
                                              short* __restrict__ outb) {
  __shared__ short As[64][136];
  __shared__ short Bs[64][136];
  int tid = threadIdx.x;
  int mg = blockIdx.x / NBLK, ng = blockIdx.x % NBLK;
  int tok0 = mg * 64, n0 = ng * 64;
  int lane = tid & 63, w = tid >> 6;
  int mw = (w & 1) * 32, nw = (w >> 1) * 32;
  floatx4 acc[2][2] = {{{0.f, 0.f, 0.f, 0.f}, {0.f, 0.f, 0.f, 0.f}},
                       {{0.f, 0.f, 0.f, 0.f}, {0.f, 0.f, 0.f, 0.f}}};
  int r2 = tid >> 4, c8 = tid & 15;
  int ml = lane & 15, kq = (lane >> 4) * 8;
  const int K = KTILES * 128;

  for (int kt = 0; kt < KTILES; ++kt) {
    const short* Asrc;
    int cb;
    if (KTILES == 4) {
      Asrc = (kt < 2) ? A0 : A1;
      cb = (kt & 1) * 128;
    } else {
      Asrc = A0;
      cb = kt * 128;
    }
#pragma unroll
    for (int pass = 0; pass < 4; ++pass) {
      int row = pass * 16 + r2;
      *(short8_t*)&As[row][c8 * 8] =
          *(const short8_t*)&Asrc[(tok0 + row) * 256 + cb + c8 * 8];
      *(short8_t*)&Bs[row][c8 * 8] =
          *(const short8_t*)&W[(n0 + row) * K + kt * 128 + c8 * 8];
    }
    __syncthreads();
#pragma unroll
    for (int s = 0; s < 4; ++s) {
      short8_t a0 = *(short8_t*)&As[mw + ml][s * 32 + kq];
      short8_t a1 = *(short8_t*)&As[mw + 16 + ml][s * 32 + kq];
      short8_t b0 = *(short8_t*)&Bs[nw + ml][s * 32 + kq];
      short8_t b1 = *(short8_t*)&Bs[nw + 16 + ml][s * 32 + kq];
      acc[0][0] = __builtin_amdgcn_mfma_f32_16x16x32_bf16(a0, b0, acc[0][0], 0, 0, 0);
      acc[0][1] = __builtin_amdgcn_mfma_f32_16x16x32_bf16(a0, b1, acc[0][1], 0, 0, 0);
      acc[1][0] = __builtin_amdgcn_mfma_f32_16x16x32_bf16(a1, b0, acc[1][0], 0, 0, 0);
      acc[1][1] = __builtin_amdgcn_mfma_f32_16x16x32_bf16(a1, b1, acc[1][1], 0, 0, 0);
    }
    __syncthreads();
  }
  int col = lane & 15, rq = (lane >> 4) * 4;
#pragma unroll
  for (int nt = 0; nt < 2; ++nt) {
    int n = n0 + nw + nt * 16 + col;
    float bv = (MODE == 0) ? 0.f : bias[n];
#pragma unroll
    for (int mt = 0; mt < 2; ++mt) {
#pragma unroll
      for (int rg = 0; rg < 4; ++rg) {
        int tok = tok0 + mw + mt * 16 + rq + rg;
        float v = acc[mt][nt][rg] + bv;
        if (MODE == 0) {
          outb[tok * 384 + n] = f2bf(v);
        } else if (MODE == 1) {
          float g = 0.5f * v * (1.f + erff(v * 0.70710678118654752f));
          outb[tok * 256 + n] = f2bf(g);
        } else {
          outf[tok * 256 + n] = xres[tok * 256 + n] + v;
        }
      }
    }
  }
}

// ---------------- gemmA3: fused gemm1 (Y = xbf@WA) + kernelA3 epilogue -----
// One block per 32-token chunk, 384 threads (6 waves), LDS-free GEMM.
// Wave w owns output cols [w*64, w*64+64). Cols 0-255 = values, 256-287 = v1,
// 288-319 = off, 320-351 = key, 352 = gate.
__global__ __launch_bounds__(384) void gemmA3(const short* __restrict__ xbf,
                                              const short* __restrict__ WA,
                                              const float* __restrict__ pos,
                                              const float* __restrict__ poff,
                                              const float* __restrict__ b_mem1v,
                                              const float* __restrict__ b_key,
                                              const float* __restrict__ b_gate,
                                              const float* __restrict__ b_val,
                                              float* __restrict__ m1cT,
                                              float* __restrict__ m1sT,
                                              float* __restrict__ qc,
                                              float* __restrict__ qs,
                                              short* __restrict__ K2bf,
                                              short* __restrict__ gvT,
                                              float* __restrict__ sg) {
  __shared__ float YL[32][132];  // cols 256..383 of Y, fp32
  __shared__ float gsh[32];
  int tid = threadIdx.x;
  int lane = tid & 63, w = tid >> 6;
  int ml = lane & 15, quad = lane >> 4, kq = quad * 8;
  int bc = blockIdx.x;
  int tok0 = bc * 32;
  floatx4 acc[2][4] = {};
  const short* A0p = &xbf[(tok0 + ml) * 256 + kq];
  const short* A1p = &xbf[(tok0 + 16 + ml) * 256 + kq];
  const short* Bp = &WA[(w * 64 + ml) * 256 + kq];
#pragma unroll
  for (int ks = 0; ks < 8; ++ks) {
    short8_t a0 = *(const short8_t*)(A0p + ks * 32);
    short8_t a1 = *(const short8_t*)(A1p + ks * 32);
#pragma unroll
    for (int nt = 0; nt < 4; ++nt) {
      short8_t b = *(const short8_t*)(Bp + nt * 16 * 256 + ks * 32);
      acc[0][nt] = __builtin_amdgcn_mfma_f32_16x16x32_bf16(a0, b, acc[0][nt], 0, 0, 0);
      acc[1][nt] = __builtin_amdgcn_mfma_f32_16x16x32_bf16(a1, b, acc[1][nt], 0, 0, 0);
    }
  }
  // waves 4,5 stage cols 256..383 into LDS (fp32, no bf16 round-trip)
  if (w >= 4) {
#pragma unroll
    for (int mt = 0; mt < 2; ++mt)
#pragma unroll
      for (int nt = 0; nt < 4; ++nt) {
        int col = (w - 4) * 64 + nt * 16 + ml;
#pragma unroll
        for (int r = 0; r < 4; ++r)
          YL[mt * 16 + quad * 4 + r][col] = acc[mt][nt][r];
      }
  }
  __syncthreads();
  // A3 elementwise phase: 32 tok x 32 p = 1024 items on threads 0..255
  if (tid < 256) {
#pragma unroll
    for (int it = 0; it < 4; ++it) {
      int idx = it * 256 + tid;
      int t = idx >> 5, p = idx & 31;
      int tok = tok0 + t, l = tok & (L_ - 1);
      int b = tok >> 11;
      float v1 = YL[t][p] + b_mem1v[p];
      float ph = pos[l * 32 + p];
      float pc = cosf(ph), ps = sinf(ph);
      int idxT = (b * 32 + p) * L_ + l;
      m1cT[idxT] = pc * v1;
      m1sT[idxT] = ps * v1;
      float off = tanhf(YL[t][32 + p] + poff[l * 32 + p]) * PI_F;
      float oc = cosf(off), os = sinf(off);
      int gidx = tok * 32 + p;
      qc[gidx] = pc * oc - ps * os;
      qs[gidx] = ps * oc + pc * os;
      float kp = tanhf(YL[t][64 + p] + b_key[p]) * PI_F;
      K2bf[tok * 64 + p] = f2bf(cosf(kp));
      K2bf[tok * 64 + 32 + p] = f2bf(sinf(kp));
      if (p == 0) {
        float g = 1.f / (1.f + expf(-(YL[t][96] + b_gate[0])));
        sg[tok] = g;
        gsh[t] = g;
      }
    }
  }
  __syncthreads();
  // gvT = (values + b_val) * gate, transposed [bc][d][t], from waves 0..3
  if (w < 4) {
#pragma unroll
    for (int nt = 0; nt < 4; ++nt) {
      int d = w * 64 + nt * 16 + ml;
      float bv = b_val[d];
#pragma unroll
      for (int mt = 0; mt < 2; ++mt) {
        int t0 = mt * 16 + quad * 4;
        short4 o;
        o.x = f2bf((acc[mt][nt][0] + bv) * gsh[t0 + 0]);
        o.y = f2bf((acc[mt][nt][1] + bv) * gsh[t0 + 1]);
        o.z = f2bf((acc[mt][nt][2] + bv) * gsh[t0 + 2]);
        o.w = f2bf((acc[mt][nt][3] + bv) * gsh[t0 + 3]);
        *(short4*)&gvT[(bc * 256 + d) * 32 + t0] = o;
      }
    }
  }
}

// ---------------- scan_all: m1 scans + sg scan + ctx prefix (ex-kernelCtx) -
// blk<128: m1cT row; blk<256: m1sT row; blk<260: sg; blk>=260: ctx -> ctxbf.
__global__ void scan_all(float* __restrict__ m1cT, float* __restrict__ m1sT,
                         float* __restrict__ sg, const float* __restrict__ x,
                         const float* __restrict__ ctxsum, short* __restrict__ ctxbf) {
  int blk = blockIdx.x;
  int tid = threadIdx.x;
  if (blk >= 260) {
    // ctx: chunk prefix of ctxsum + local scan -> ctxbf (bf16)
    int c2 = blk - 260;
    int b = c2 >> 6, ch = c2 & 63;
    float run = 0.f;
    int sb = b * 64 * 256 + tid;
    for (int c = 0; c < ch; ++c) run += ctxsum[sb + c * 256];
    int xb = (b * L_ + ch * 32) * 256 + tid;
#pragma unroll 8
    for (int i = 0; i < 32; ++i) {
      run += x[xb + i * 256];
      int l = ch * 32 + i;
      ctxbf[xb + i * 256] = f2bf(run / (float)(l + 1));
    }
    return;
  }
  int lane = tid & 63, wid = tid >> 6;
  __shared__ float wsum[4];
  float carry = 0.f;
  float* arr;
  int base;
  if (blk < 256) {
    arr = (blk < 128) ? m1cT : m1sT;
    base = (blk & 127) * L_;
  } else {
    arr = sg;
    base = (blk - 256) * L_;
  }
  for (int t0 = 0; t0 < L_; t0 += 256) {
    int l = t0 + tid;
    float v = arr[base + l];
#pragma unroll
    for (int off = 1; off < 64; off <<= 1) {
      float n = __shfl_up(v, off, 64);
      if (lane >= off) v += n;
    }
    if (lane == 63) wsum[wid] = v;
    __syncthreads();
    float add = carry;
    for (int w = 0; w < wid; ++w) add += wsum[w];
    arr[base + l] = v + add;
    carry += wsum[0] + wsum[1] + wsum[2] + wsum[3];
    __syncthreads();
  }
}

// ---------------- Kernel CD: storage phases (MFMA) + per-chunk U sums ------
// Writes SPbf [tok][64] and UT bf16 [bc][d][q] (pre-transposed for E/FG).
__global__ __launch_bounds__(256) void kernelCD(const short* __restrict__ hs,
                                                const short* __restrict__ W2T,
                                                const float* __restrict__ b_sk2,
                                                const short* __restrict__ gvT,
                                                short* __restrict__ SPbf,
                                                short* __restrict__ UT) {
  __shared__ __align__(16) short SPL[2][64][40];
  int tid = threadIdx.x;
  int tok0 = blockIdx.x * 64;
  int lane = tid & 63, w = tid >> 6;
  int ml = lane & 15, quad = lane >> 4, kq = quad * 8;
  int m0 = w * 16;
  floatx4 pacc[2] = {};
#pragma unroll
  for (int s = 0; s < 8; ++s) {
    short8_t a = *(const short8_t*)&hs[(tok0 + m0 + ml) * 256 + s * 32 + kq];
    short8_t b0 = *(const short8_t*)&W2T[ml * 256 + s * 32 + kq];
    short8_t b1 = *(const short8_t*)&W2T[(16 + ml) * 256 + s * 32 + kq];
    pacc[0] = __builtin_amdgcn_mfma_f32_16x16x32_bf16(a, b0, pacc[0], 0, 0, 0);
    pacc[1] = __builtin_amdgcn_mfma_f32_16x16x32_bf16(a, b1, pacc[1], 0, 0, 0);
  }
  int cl = w >> 1;
#pragma unroll
  for (int nt = 0; nt < 2; ++nt) {
    int p = nt * 16 + ml;
    float bs = b_sk2[p];
#pragma unroll
    for (int r = 0; r < 4; ++r) {
      int tok = tok0 + m0 + quad * 4 + r;
      float sp = tanhf(pacc[nt][r] + bs) * PI_F;
      short c = f2bf(cosf(sp)), s = f2bf(sinf(sp));
      int tl = (w & 1) * 16 + quad * 4 + r;
      SPL[cl][p][tl] = c;
      SPL[cl][32 + p][tl] = s;
      SPbf[tok * 64 + p] = c;
      SPbf[tok * 64 + 32 + p] = s;
    }
  }
  __syncthreads();
  int c2 = w & 1, dbase = (w >> 1) * 128;
  int bc = blockIdx.x * 2 + c2;
  short8_t a[4];
#pragma unroll
  for (int mt = 0; mt < 4; ++mt) a[mt] = *(short8_t*)&SPL[c2][mt * 16 + ml][kq];
#pragma unroll
  for (int dp = 0; dp < 2; ++dp) {
    floatx4 acc[4][4] = {};
#pragma unroll
    for (int nt = 0; nt < 4; ++nt) {
      short8_t b = *(const short8_t*)&gvT[(bc * 256 + dbase + dp * 64 + nt * 16 + ml) * 32 + kq];
#pragma unroll
      for (int mt = 0; mt < 4; ++mt)
        acc[mt][nt] = __builtin_amdgcn_mfma_f32_16x16x32_bf16(a[mt], b, acc[mt][nt], 0, 0, 0);
    }
#pragma unroll
    for (int mt = 0; mt < 4; ++mt)
#pragma unroll
      for (int nt = 0; nt < 4; ++nt)
#pragma unroll
        for (int r = 0; r < 4; ++r) {
          int q = mt * 16 + quad * 4 + r;
          int d = dbase + dp * 64 + nt * 16 + ml;
          UT[(bc * 256 + d) * 64 + q] = f2bf(acc[mt][nt][r]);
        }
  }
}

// ---------------- Kernel E: in-place exclusive prefix over chunks (bf16) ---
__global__ void kernelE(short* __restrict__ UT) {
  int tid = blockIdx.x * 256 + threadIdx.x;  // B*256d*64q = 65536
  int q = tid & 63;
  int d = (tid >> 6) & 255;
  int b = tid >> 14;
  int base = ((b * NC) * 256 + d) * 64 + q;
  const int cs = 256 * 64;
  float run = 0.f;
  for (int c0 = 0; c0 < NC; c0 += 8) {
    short v[8];
#pragma unroll
    for (int j = 0; j < 8; ++j) v[j] = UT[base + (c0 + j) * cs];
#pragma unroll
    for (int j = 0; j < 8; ++j) {
      UT[base + (c0 + j) * cs] = f2bf(run);
      run += bf2f(v[j]);
    }
  }
}

// ---------------- Kernel FG: retrieval + pos_out + LN -> cbn ---------------
// U B-frags load directly from UT (global, bf16, pre-transposed) — no staging.
__global__ __launch_bounds__(256) void kernelFG(const short* __restrict__ UT,
                                                const short* __restrict__ SPbf,
                                                const short* __restrict__ K2bf,
                                                const short* __restrict__ gvT,
                                                const float* __restrict__ sgc,
                                                const float* __restrict__ m1cT,
                                                const float* __restrict__ m1sT,
                                                const float* __restrict__ qc,
                                                const float* __restrict__ qs,
                                                const short* __restrict__ W1OT,
                                                const float* __restrict__ b_mem1o,
                                                const float* __restrict__ ln_g,
                                                const float* __restrict__ ln_b,
                                                short* __restrict__ cbn) {
  __shared__ __align__(16) short SL[32][40];   // masked S [t][s]
  __shared__ __align__(16) short PR[32][40];   // pr [t][p]
  __shared__ float CMB[32][260];
  __shared__ float scl[32], mu_s[32], rs_s[32];
  int tid = threadIdx.x;
  int bc = blockIdx.x;
  int lbase = bc * CL;
  int bb = bc >> 6, lloc = (bc & 63) * 32;
  if (tid < 32) scl[tid] = rsqrtf(fmaxf(sgc[lbase + tid], 1.f)) * INV_SQRT_P;
  // pr = (m1c*qc + m1s*qs)/sqrt(P), bf16 into PR[t][p]
  for (int it = 0; it < 4; ++it) {
    int i = it * 256 + tid;
    int p = i >> 5, t = i & 31;
    int gT = (bb * 32 + p) * L_ + lloc + t;
    int g = (lbase + t) * 32 + p;
    PR[t][p] = f2bf((m1cT[gT] * qc[g] + m1sT[gT] * qs[g]) * INV_SQRT_P);
  }
  int lane = tid & 63, w = tid >> 6;
  int ml = lane & 15, quad = lane >> 4, kq = quad * 8;
  floatx4 acc[2][4] = {};
  short8_t ka0 = *(const short8_t*)&K2bf[(lbase + ml) * 64 + kq];
  short8_t ka1 = *(const short8_t*)&K2bf[(lbase + 16 + ml) * 64 + kq];
  short8_t kb0 = *(const short8_t*)&K2bf[(lbase + ml) * 64 + 32 + kq];
  short8_t kb1 = *(const short8_t*)&K2bf[(lbase + 16 + ml) * 64 + 32 + kq];
  // Part 1, ks=0: K2[:,0:32] @ Uprev[0:32,:]  (B-frag from UT global)
#pragma unroll
  for (int nt = 0; nt < 4; ++nt) {
    short8_t b = *(const short8_t*)&UT[(bc * 256 + w * 64 + nt * 16 + ml) * 64 + kq];
    acc[0][nt] = __builtin_amdgcn_mfma_f32_16x16x32_bf16(ka0, b, acc[0][nt], 0, 0, 0);
    acc[1][nt] = __builtin_amdgcn_mfma_f32_16x16x32_bf16(ka1, b, acc[1][nt], 0, 0, 0);
  }
  // wave 0: S = K2 @ SP^T, mask, write SL[t][s]
  if (w == 0) {
    floatx4 sacc[2][2] = {};
#pragma unroll
    for (int ks2 = 0; ks2 < 2; ++ks2) {
      short8_t a0 = (ks2 == 0) ? ka0 : kb0;
      short8_t a1 = (ks2 == 0) ? ka1 : kb1;
      short8_t b0 = *(const short8_t*)&SPbf[(lbase + ml) * 64 + ks2 * 32 + kq];
      short8_t b1 = *(const short8_t*)&SPbf[(lbase + 16 + ml) * 64 + ks2 * 32 + kq];
      sacc[0][0] = __builtin_amdgcn_mfma_f32_16x16x32_bf16(a0, b0, sacc[0][0], 0, 0, 0);
      sacc[0][1] = __builtin_amdgcn_mfma_f32_16x16x32_bf16(a0, b1, sacc[0][1], 0, 0, 0);
      sacc[1][0] = __builtin_amdgcn_mfma_f32_16x16x32_bf16(a1, b0, sacc[1][0], 0, 0, 0);
      sacc[1][1] = __builtin_amdgcn_mfma_f32_16x16x32_bf16(a1, b1, sacc[1][1], 0, 0, 0);
    }
#pragma unroll
    for (int mt = 0; mt < 2; ++mt)
#pragma unroll
      for (int nt = 0; nt < 2; ++nt)
#pragma unroll
        for (int r = 0; r < 4; ++r) {
          int trow = mt * 16 + quad * 4 + r;
          int scol = nt * 16 + ml;
          float v = (scol <= trow) ? sacc[mt][nt][r] : 0.f;
          SL[trow][scol] = f2bf(v);
        }
  }
  __syncthreads();
  // Part 1, ks=1: K2[:,32:64] @ Uprev[32:64,:]
#pragma unroll
  for (int nt = 0; nt < 4; ++nt) {
    short8_t b = *(const short8_t*)&UT[(bc * 256 + w * 64 + nt * 16 + ml) * 64 + 32 + kq];
    acc[0][nt] = __builtin_amdgcn_mfma_f32_16x16x32_bf16(kb0, b, acc[0][nt], 0, 0, 0);
    acc[1][nt] = __builtin_amdgcn_mfma_f32_16x16x32_bf16(kb1, b, acc[1][nt], 0, 0, 0);
  }
  // Part 2: S @ gv
  {
    short8_t a0 = *(short8_t*)&SL[ml][kq];
    short8_t a1 = *(short8_t*)&SL[16 + ml][kq];
#pragma unroll
    for (int nt = 0; nt < 4; ++nt) {
      short8_t b = *(const short8_t*)&gvT[(bc * 256 + w * 64 + nt * 16 + ml) * 32 + kq];
      acc[0][nt] = __builtin_amdgcn_mfma_f32_16x16x32_bf16(a0, b, acc[0][nt], 0, 0, 0);
      acc[1][nt] = __builtin_amdgcn_mfma_f32_16x16x32_bf16(a1, b, acc[1][nt], 0, 0, 0);
    }
  }
  // pos_out MFMA: PR[t][p] @ W1OT[d][p]^T, K=32
  floatx4 macc[2][4] = {};
  {
    short8_t a0 = *(short8_t*)&PR[ml][kq];
    short8_t a1 = *(short8_t*)&PR[16 + ml][kq];
#pragma unroll
    for (int nt = 0; nt < 4; ++nt) {
      short8_t b = *(const short8_t*)&W1OT[(w * 64 + nt * 16 + ml) * 32 + kq];
      macc[0][nt] = __builtin_amdgcn_mfma_f32_16x16x32_bf16(a0, b, macc[0][nt], 0, 0, 0);
      macc[1][nt] = __builtin_amdgcn_mfma_f32_16x16x32_bf16(a1, b, macc[1][nt], 0, 0, 0);
    }
  }
#pragma unroll
  for (int mt = 0; mt < 2; ++mt)
#pragma unroll
    for (int nt = 0; nt < 4; ++nt) {
      int d = w * 64 + nt * 16 + ml;
      float bm = b_mem1o[d];
#pragma unroll
      for (int r = 0; r < 4; ++r) {
        int t = mt * 16 + quad * 4 + r;
        CMB[t][d] = acc[mt][nt][r] * scl[t] + macc[mt][nt][r] + bm;
      }
    }
  __syncthreads();
  {
    int t = tid >> 3, g = tid & 7;
    float s = 0.f, s2 = 0.f;
#pragma unroll
    for (int j = 0; j < 32; ++j) {
      float v = CMB[t][g + j * 8];
      s += v;
      s2 += v * v;
    }
#pragma unroll
    for (int m = 1; m < 8; m <<= 1) {
      s += __shfl_xor(s, m, 64);
      s2 += __shfl_xor(s2, m, 64);
    }
    if (g == 0) {
      float mu = s / (float)D_;
      float var = s2 / (float)D_ - mu * mu;
      mu_s[t] = mu;
      rs_s[t] = rsqrtf(var + 1e-5f);
    }
  }
  __syncthreads();
  {
    float lg = ln_g[tid], lb = ln_b[tid];
#pragma unroll
    for (int t = 0; t < 32; ++t)
      cbn[(lbase + t) * 256 + tid] = f2bf((CMB[t][tid] - mu_s[t]) * rs_s[t] * lg + lb);
  }
}

extern "C" void kernel_launch(void* const* d_in, const int* in_sizes, int n_in,
                              void* d_out, int out_size, void* d_ws, size_t ws_size,
                              hipStream_t stream) {
  const float* x = (const float*)d_in[0];
  const float* pos = (const float*)d_in[1];
  const float* w_mem1v = (const float*)d_in[2];
  const float* b_mem1v = (const float*)d_in[3];
  const float* w_mem1o = (const float*)d_in[4];
  const float* b_mem1o = (const float*)d_in[5];
  const float* w_off = (const float*)d_in[6];
  const float* b_off = (const float*)d_in[7];
  const float* w_key = (const float*)d_in[8];
  const float* b_key = (const float*)d_in[9];
  const float* w_val = (const float*)d_in[10];
  const float* b_val = (const float*)d_in[11];
  const float* w_sk1 = (const float*)d_in[12];
  const float* b_sk1 = (const float*)d_in[13];
  const float* w_sk2 = (const float*)d_in[14];
  const float* b_sk2 = (const float*)d_in[15];
  const float* w_gate = (const float*)d_in[16];
  const float* b_gate = (const float*)d_in[17];
  const float* ln_g = (const float*)d_in[18];
  const float* ln_b = (const float*)d_in[19];
  const float* w_out = (const float*)d_in[20];
  const float* b_out = (const float*)d_in[21];
  float* out = (float*)d_out;
  float* ws = (float*)d_ws;

  const int BLP = B_ * L_ * P_;  // 262144
  const int BLD = B_ * L_ * D_;  // 2097152
  float* m1cT = ws;
  float* m1sT = m1cT + BLP;
  float* qc = m1sT + BLP;
  float* qs = qc + BLP;
  float* sg = qs + BLP;
  float* poff = sg + B_ * L_;
  float* ctxsum = poff + L_ * P_;              // B*64*256 = 65536 floats
  short* UT = (short*)(ctxsum + B_ * 64 * 256);
  short* xbf = UT + (size_t)B_ * NC * 256 * 64;
  short* cbn = xbf;                   // aliases xbf (dead after gemm2)
  short* ctxbf = xbf + BLD;
  short* hs = ctxbf + BLD;
  short* gvT = hs + BLD;
  short* K2bf = gvT + BLD;            // B*L*64
  short* SPbf = K2bf + B_ * L_ * 64;  // B*L*64
  short* WA = SPbf + B_ * L_ * 64;
  short* W1 = WA + 384 * 256;
  short* WO = W1 + 256 * 512;
  short* W2T = WO + 256 * 256;
  short* W1OT = W2T + 32 * 256;

  wprep<<<3776, 256, 0, stream>>>(x, pos, w_val, w_mem1v, w_off, b_off, w_key, w_gate,
                                  w_sk1, w_out, w_sk2, w_mem1o, WA, W1, WO, W2T, W1OT,
                                  xbf, poff, ctxsum);
  gemmA3<<<256, 384, 0, stream>>>(xbf, WA, pos, poff, b_mem1v, b_key, b_gate, b_val,
                                  m1cT, m1sT, qc, qs, K2bf, gvT, sg);
  scan_all<<<516, 256, 0, stream>>>(m1cT, m1sT, sg, x, ctxsum, ctxbf);
  gemm_k<4, 4, 1><<<128 * 4, 256, 0, stream>>>(xbf, ctxbf, W1, b_sk1, nullptr, nullptr, hs);
  kernelCD<<<(B_ * L_) / 64, 256, 0, stream>>>(hs, W2T, b_sk2, gvT, SPbf, UT);
  kernelE<<<256, 256, 0, stream>>>(UT);
  kernelFG<<<B_ * NC, 256, 0, stream>>>(UT, SPbf, K2bf, gvT, sg, m1cT, m1sT, qc, qs,
                                        W1OT, b_mem1o, ln_g, ln_b, cbn);
  gemm_k<2, 4, 2><<<128 * 4, 256, 0, stream>>>(cbn, nullptr, WO, b_out, x, out, nullptr);
}

// Round 2
// 180.281 us; speedup vs baseline: 1.0410x; 1.0366x over previous
//
#include <hip/hip_runtime.h>
#include <hip/hip_bf16.h>

constexpr int B_ = 4;
constexpr int L_ = 2048;
constexpr int D_ = 256;
constexpr int P_ = 32;
constexpr int CL = 32;   // chunk length for KV scan
constexpr int NC = L_ / CL;  // 64 chunks

#define PI_F 3.14159265358979323846f
#define INV_SQRT_P 0.17677669529663687f  // 1/sqrt(32)

typedef __attribute__((ext_vector_type(8))) short short8_t;
typedef __attribute__((ext_vector_type(4))) float floatx4;

static __device__ inline short f2bf(float f) {
  unsigned int u;
  __builtin_memcpy(&u, &f, 4);
  unsigned int r = (u + 0x7fffu + ((u >> 16) & 1u)) >> 16;
  return (short)r;
}
static __device__ inline float bf2f(short s) {
  unsigned int u = ((unsigned int)(unsigned short)s) << 16;
  float f;
  __builtin_memcpy(&f, &u, 4);
  return f;
}

// ---------------- wprep: weight casts/transposes + x->bf16 + poff + ctxsum -
__global__ void wprep(const float* __restrict__ x, const float* __restrict__ pos,
                      const float* __restrict__ w_val, const float* __restrict__ w_mem1v,
                      const float* __restrict__ w_off, const float* __restrict__ b_off,
                      const float* __restrict__ w_key, const float* __restrict__ w_gate,
                      const float* __restrict__ w_sk1, const float* __restrict__ w_out,
                      const float* __restrict__ w_sk2, const float* __restrict__ w_mem1o,
                      short* __restrict__ WA, short* __restrict__ W1,
                      short* __restrict__ WO, short* __restrict__ W2T,
                      short* __restrict__ W1OT,
                      short* __restrict__ xbf, float* __restrict__ poff,
                      float* __restrict__ ctxsum) {
  int blk = blockIdx.x, tid = threadIdx.x;
  if (blk < 384) {
    int idx = blk * 256 + tid;
    int n = idx >> 8, k = idx & 255;
    float v;
    if (n < 256) v = w_val[k * 256 + n];
    else if (n < 288) v = w_mem1v[k * 32 + (n - 256)];
    else if (n < 320) v = w_off[k * 32 + (n - 288)];
    else if (n < 352) v = w_key[k * 32 + (n - 320)];
    else if (n == 352) v = w_gate[k];
    else v = 0.f;
    WA[idx] = f2bf(v);
  } else if (blk < 896) {
    int idx = (blk - 384) * 256 + tid;
    int n = idx >> 9, k = idx & 511;
    W1[idx] = f2bf(w_sk1[k * 256 + n]);
  } else if (blk < 1152) {
    int idx = (blk - 896) * 256 + tid;
    int n = idx >> 8, k = idx & 255;
    WO[idx] = f2bf(w_out[k * 256 + n]);
  } else if (blk < 1184) {
    int idx = (blk - 1152) * 256 + tid;  // p*256 + k
    int p = idx >> 8, k = idx & 255;
    W2T[idx] = f2bf(w_sk2[k * 32 + p]);
  } else if (blk < 1216) {
    int idx = (blk - 1184) * 256 + tid;  // d*32 + p
    int d = idx >> 5, p = idx & 31;
    W1OT[idx] = f2bf(w_mem1o[p * 256 + d]);
  } else if (blk < 3264) {
    int idx = ((blk - 1216) * 256 + tid) * 4;
    float4 v = *(const float4*)&x[idx];
    short4 o;
    o.x = f2bf(v.x); o.y = f2bf(v.y); o.z = f2bf(v.z); o.w = f2bf(v.w);
    *(short4*)&xbf[idx] = o;
  } else if (blk < 3520) {
    int idx = (blk - 3264) * 256 + tid;
    int l = idx >> 5, p = idx & 31;
    float a = b_off[p];
    for (int j = 0; j < 32; ++j) a += pos[l * 32 + j] * w_off[(256 + j) * 32 + p];
    poff[idx] = a;
  } else {
    // ctx chunk sums: depends only on x
    int c2 = blk - 3520;
    int b = c2 >> 6, ch = c2 & 63;
    int xb = (b * L_ + ch * 32) * 256 + tid;
    float s = 0.f;
#pragma unroll 8
    for (int i = 0; i < 32; ++i) s += x[xb + i * 256];
    ctxsum[c2 * 256 + tid] = s;
  }
}

// ---------------- generic bf16 MFMA GEMM, 64x64 tile -----------------------
// MODE 1: hs bf16 = gelu(A @ W + bias)
// MODE 2: out fp32 = xres + A0 @ W + bias
template <int KTILES, int NBLK, int MODE>
__global__ __launch_bounds__(256) void gemm_k(const short* __restrict__ A0,
                                              const short* __restrict__ A1,
                                              const short* __restrict__ W,
                                              const float* __restrict__ bias,
                                              const float* __restrict__ xres,
                                              float* __restrict__ outf,
                                              short* __restrict__ outb) {
  __shared__ short As[64][136];
  __shared__ short Bs[64][136];
  int tid = threadIdx.x;
  int mg = blockIdx.x / NBLK, ng = blockIdx.x % NBLK;
  int tok0 = mg * 64, n0 = ng * 64;
  int lane = tid & 63, w = tid >> 6;
  int mw = (w & 1) * 32, nw = (w >> 1) * 32;
  floatx4 acc[2][2] = {{{0.f, 0.f, 0.f, 0.f}, {0.f, 0.f, 0.f, 0.f}},
                       {{0.f, 0.f, 0.f, 0.f}, {0.f, 0.f, 0.f, 0.f}}};
  int r2 = tid >> 4, c8 = tid & 15;
  int ml = lane & 15, kq = (lane >> 4) * 8;
  const int K = KTILES * 128;

  for (int kt = 0; kt < KTILES; ++kt) {
    const short* Asrc;
    int cb;
    if (KTILES == 4) {
      Asrc = (kt < 2) ? A0 : A1;
      cb = (kt & 1) * 128;
    } else {
      Asrc = A0;
      cb = kt * 128;
    }
#pragma unroll
    for (int pass = 0; pass < 4; ++pass) {
      int row = pass * 16 + r2;
      *(short8_t*)&As[row][c8 * 8] =
          *(const short8_t*)&Asrc[(tok0 + row) * 256 + cb + c8 * 8];
      *(short8_t*)&Bs[row][c8 * 8] =
          *(const short8_t*)&W[(n0 + row) * K + kt * 128 + c8 * 8];
    }
    __syncthreads();
#pragma unroll
    for (int s = 0; s < 4; ++s) {
      short8_t a0 = *(short8_t*)&As[mw + ml][s * 32 + kq];
      short8_t a1 = *(short8_t*)&As[mw + 16 + ml][s * 32 + kq];
      short8_t b0 = *(short8_t*)&Bs[nw + ml][s * 32 + kq];
      short8_t b1 = *(short8_t*)&Bs[nw + 16 + ml][s * 32 + kq];
      acc[0][0] = __builtin_amdgcn_mfma_f32_16x16x32_bf16(a0, b0, acc[0][0], 0, 0, 0);
      acc[0][1] = __builtin_amdgcn_mfma_f32_16x16x32_bf16(a0, b1, acc[0][1], 0, 0, 0);
      acc[1][0] = __builtin_amdgcn_mfma_f32_16x16x32_bf16(a1, b0, acc[1][0], 0, 0, 0);
      acc[1][1] = __builtin_amdgcn_mfma_f32_16x16x32_bf16(a1, b1, acc[1][1], 0, 0, 0);
    }
    __syncthreads();
  }
  int col = lane & 15, rq = (lane >> 4) * 4;
#pragma unroll
  for (int nt = 0; nt < 2; ++nt) {
    int n = n0 + nw + nt * 16 + col;
    float bv = (MODE == 0) ? 0.f : bias[n];
#pragma unroll
    for (int mt = 0; mt < 2; ++mt) {
#pragma unroll
      for (int rg = 0; rg < 4; ++rg) {
        int tok = tok0 + mw + mt * 16 + rq + rg;
        float v = acc[mt][nt][rg] + bv;
        if (MODE == 0) {
          outb[tok * 384 + n] = f2bf(v);
        } else if (MODE == 1) {
          float g = 0.5f * v * (1.f + erff(v * 0.70710678118654752f));
          outb[tok * 256 + n] = f2bf(g);
        } else {
          outf[tok * 256 + n] = xres[tok * 256 + n] + v;
        }
      }
    }
  }
}

// ---------------- gemmA3: fused gemm1 (Y = xbf@WA) + kernelA3 epilogue -----
__global__ __launch_bounds__(384) void gemmA3(const short* __restrict__ xbf,
                                              const short* __restrict__ WA,
                                              const float* __restrict__ pos,
                                              const float* __restrict__ poff,
                                              const float* __restrict__ b_mem1v,
                                              const float* __restrict__ b_key,
                                              const float* __restrict__ b_gate,
                                              const float* __restrict__ b_val,
                                              float* __restrict__ m1cT,
                                              float* __restrict__ m1sT,
                                              float* __restrict__ qc,
                                              float* __restrict__ qs,
                                              short* __restrict__ K2bf,
                                              short* __restrict__ gvT,
                                              float* __restrict__ sg) {
  __shared__ float YL[32][132];  // cols 256..383 of Y, fp32
  __shared__ float gsh[32];
  int tid = threadIdx.x;
  int lane = tid & 63, w = tid >> 6;
  int ml = lane & 15, quad = lane >> 4, kq = quad * 8;
  int bc = blockIdx.x;
  int tok0 = bc * 32;
  floatx4 acc[2][4] = {};
  const short* A0p = &xbf[(tok0 + ml) * 256 + kq];
  const short* A1p = &xbf[(tok0 + 16 + ml) * 256 + kq];
  const short* Bp = &WA[(w * 64 + ml) * 256 + kq];
#pragma unroll
  for (int ks = 0; ks < 8; ++ks) {
    short8_t a0 = *(const short8_t*)(A0p + ks * 32);
    short8_t a1 = *(const short8_t*)(A1p + ks * 32);
#pragma unroll
    for (int nt = 0; nt < 4; ++nt) {
      short8_t b = *(const short8_t*)(Bp + nt * 16 * 256 + ks * 32);
      acc[0][nt] = __builtin_amdgcn_mfma_f32_16x16x32_bf16(a0, b, acc[0][nt], 0, 0, 0);
      acc[1][nt] = __builtin_amdgcn_mfma_f32_16x16x32_bf16(a1, b, acc[1][nt], 0, 0, 0);
    }
  }
  // waves 4,5 stage cols 256..383 into LDS (fp32, no bf16 round-trip)
  if (w >= 4) {
#pragma unroll
    for (int mt = 0; mt < 2; ++mt)
#pragma unroll
      for (int nt = 0; nt < 4; ++nt) {
        int col = (w - 4) * 64 + nt * 16 + ml;
#pragma unroll
        for (int r = 0; r < 4; ++r)
          YL[mt * 16 + quad * 4 + r][col] = acc[mt][nt][r];
      }
  }
  __syncthreads();
  // A3 elementwise phase: 32 tok x 32 p = 1024 items on threads 0..255
  if (tid < 256) {
#pragma unroll
    for (int it = 0; it < 4; ++it) {
      int idx = it * 256 + tid;
      int t = idx >> 5, p = idx & 31;
      int tok = tok0 + t, l = tok & (L_ - 1);
      int b = tok >> 11;
      float v1 = YL[t][p] + b_mem1v[p];
      float ph = pos[l * 32 + p];
      float pc = cosf(ph), ps = sinf(ph);
      int idxT = (b * 32 + p) * L_ + l;
      m1cT[idxT] = pc * v1;
      m1sT[idxT] = ps * v1;
      float off = tanhf(YL[t][32 + p] + poff[l * 32 + p]) * PI_F;
      float oc = cosf(off), os = sinf(off);
      int gidx = tok * 32 + p;
      qc[gidx] = pc * oc - ps * os;
      qs[gidx] = ps * oc + pc * os;
      float kp = tanhf(YL[t][64 + p] + b_key[p]) * PI_F;
      K2bf[tok * 64 + p] = f2bf(cosf(kp));
      K2bf[tok * 64 + 32 + p] = f2bf(sinf(kp));
      if (p == 0) {
        float g = 1.f / (1.f + expf(-(YL[t][96] + b_gate[0])));
        sg[tok] = g;
        gsh[t] = g;
      }
    }
  }
  __syncthreads();
  // gvT = (values + b_val) * gate, transposed [bc][d][t], from waves 0..3
  if (w < 4) {
#pragma unroll
    for (int nt = 0; nt < 4; ++nt) {
      int d = w * 64 + nt * 16 + ml;
      float bv = b_val[d];
#pragma unroll
      for (int mt = 0; mt < 2; ++mt) {
        int t0 = mt * 16 + quad * 4;
        short4 o;
        o.x = f2bf((acc[mt][nt][0] + bv) * gsh[t0 + 0]);
        o.y = f2bf((acc[mt][nt][1] + bv) * gsh[t0 + 1]);
        o.z = f2bf((acc[mt][nt][2] + bv) * gsh[t0 + 2]);
        o.w = f2bf((acc[mt][nt][3] + bv) * gsh[t0 + 3]);
        *(short4*)&gvT[(bc * 256 + d) * 32 + t0] = o;
      }
    }
  }
}

// ---------------- scan_all: m1 scans + sg scan + ctx prefix ----------------
// blk<128: m1cT row; blk<256: m1sT row; blk<260: sg; blk>=260: ctx -> ctxbf.
// All 8 row-chunks preloaded into registers BEFORE scanning (one latency
// round instead of 8 serial {load->scan->store} rounds).
__global__ void scan_all(float* __restrict__ m1cT, float* __restrict__ m1sT,
                         float* __restrict__ sg, const float* __restrict__ x,
                         const float* __restrict__ ctxsum, short* __restrict__ ctxbf) {
  int blk = blockIdx.x;
  int tid = threadIdx.x;
  if (blk >= 260) {
    // ctx: chunk prefix of ctxsum + local scan -> ctxbf (bf16)
    int c2 = blk - 260;
    int b = c2 >> 6, ch = c2 & 63;
    float run = 0.f;
    int sb = b * 64 * 256 + tid;
    for (int c = 0; c < ch; ++c) run += ctxsum[sb + c * 256];
    int xb = (b * L_ + ch * 32) * 256 + tid;
#pragma unroll 8
    for (int i = 0; i < 32; ++i) {
      run += x[xb + i * 256];
      int l = ch * 32 + i;
      ctxbf[xb + i * 256] = f2bf(run / (float)(l + 1));
    }
    return;
  }
  int lane = tid & 63, wid = tid >> 6;
  __shared__ float wsum[4];
  float carry = 0.f;
  float* arr;
  int base;
  if (blk < 256) {
    arr = (blk < 128) ? m1cT : m1sT;
    base = (blk & 127) * L_;
  } else {
    arr = sg;
    base = (blk - 256) * L_;
  }
  float v[8];
#pragma unroll
  for (int i = 0; i < 8; ++i) v[i] = arr[base + i * 256 + tid];
#pragma unroll
  for (int i = 0; i < 8; ++i) {
    float vv = v[i];
#pragma unroll
    for (int off = 1; off < 64; off <<= 1) {
      float n = __shfl_up(vv, off, 64);
      if (lane >= off) vv += n;
    }
    if (lane == 63) wsum[wid] = vv;
    __syncthreads();
    float add = carry;
    for (int w = 0; w < wid; ++w) add += wsum[w];
    arr[base + i * 256 + tid] = vv + add;
    carry += wsum[0] + wsum[1] + wsum[2] + wsum[3];
    __syncthreads();
  }
}

// ---------------- Kernel CD: storage phases (MFMA) + per-chunk U sums ------
// One block per 32-token chunk (256 blocks, all CUs active).
// Phase 1: wave w computes SP for token-half (w&1), p-half (w>>1).
// Phase 2: wave w computes U[q][d] for d in [w*64, w*64+64).
__global__ __launch_bounds__(256) void kernelCD(const short* __restrict__ hs,
                                                const short* __restrict__ W2T,
                                                const float* __restrict__ b_sk2,
                                                const short* __restrict__ gvT,
                                                short* __restrict__ SPbf,
                                                short* __restrict__ UT) {
  __shared__ __align__(16) short SPL[64][40];
  int tid = threadIdx.x;
  int bc = blockIdx.x;
  int tok0 = bc * 32;
  int lane = tid & 63, w = tid >> 6;
  int ml = lane & 15, quad = lane >> 4, kq = quad * 8;
  int th = w & 1, ph = w >> 1;
  floatx4 pacc = {};
#pragma unroll
  for (int s = 0; s < 8; ++s) {
    short8_t a = *(const short8_t*)&hs[(tok0 + th * 16 + ml) * 256 + s * 32 + kq];
    short8_t b0 = *(const short8_t*)&W2T[(ph * 16 + ml) * 256 + s * 32 + kq];
    pacc = __builtin_amdgcn_mfma_f32_16x16x32_bf16(a, b0, pacc, 0, 0, 0);
  }
  {
    int p = ph * 16 + ml;
    float bs = b_sk2[p];
#pragma unroll
    for (int r = 0; r < 4; ++r) {
      int tl = th * 16 + quad * 4 + r;
      int tok = tok0 + tl;
      float sp = tanhf(pacc[r] + bs) * PI_F;
      short c = f2bf(cosf(sp)), s = f2bf(sinf(sp));
      SPL[p][tl] = c;
      SPL[32 + p][tl] = s;
      SPbf[tok * 64 + p] = c;
      SPbf[tok * 64 + 32 + p] = s;
    }
  }
  __syncthreads();
  short8_t a[4];
#pragma unroll
  for (int mt = 0; mt < 4; ++mt) a[mt] = *(short8_t*)&SPL[mt * 16 + ml][kq];
  floatx4 acc[4][4] = {};
#pragma unroll
  for (int nt = 0; nt < 4; ++nt) {
    short8_t b = *(const short8_t*)&gvT[(bc * 256 + w * 64 + nt * 16 + ml) * 32 + kq];
#pragma unroll
    for (int mt = 0; mt < 4; ++mt)
      acc[mt][nt] = __builtin_amdgcn_mfma_f32_16x16x32_bf16(a[mt], b, acc[mt][nt], 0, 0, 0);
  }
#pragma unroll
  for (int mt = 0; mt < 4; ++mt)
#pragma unroll
    for (int nt = 0; nt < 4; ++nt)
#pragma unroll
      for (int r = 0; r < 4; ++r) {
        int q = mt * 16 + quad * 4 + r;
        int d = w * 64 + nt * 16 + ml;
        UT[(bc * 256 + d) * 64 + q] = f2bf(acc[mt][nt][r]);
      }
}

// ---------------- Kernel E: in-place exclusive prefix over chunks (bf16) ---
// All 64 values preloaded into registers first (one latency round, fully
// pipelined loads) -> compiler can't pipeline across the old RMW groups.
__global__ void kernelE(short* __restrict__ UT) {
  int tid = blockIdx.x * 256 + threadIdx.x;  // B*256d*64q = 65536
  int q = tid & 63;
  int d = (tid >> 6) & 255;
  int b = tid >> 14;
  int base = ((b * NC) * 256 + d) * 64 + q;
  const int cs = 256 * 64;
  short v[64];
#pragma unroll
  for (int c = 0; c < 64; ++c) v[c] = UT[base + c * cs];
  float run = 0.f;
#pragma unroll
  for (int c = 0; c < 64; ++c) {
    UT[base + c * cs] = f2bf(run);
    run += bf2f(v[c]);
  }
}

// ---------------- Kernel FG: retrieval + pos_out + LN -> cbn ---------------
// 512 threads / 8 waves: wave w owns d-columns [w*32, w*32+32). 2 waves/SIMD
// for latency hiding; wave 0 additionally computes the S score tile.
__global__ __launch_bounds__(512) void kernelFG(const short* __restrict__ UT,
                                                const short* __restrict__ SPbf,
                                                const short* __restrict__ K2bf,
                                                const short* __restrict__ gvT,
                                                const float* __restrict__ sgc,
                                                const float* __restrict__ m1cT,
                                                const float* __restrict__ m1sT,
                                                const float* __restrict__ qc,
                                                const float* __restrict__ qs,
                                                const short* __restrict__ W1OT,
                                                const float* __restrict__ b_mem1o,
                                                const float* __restrict__ ln_g,
                                                const float* __restrict__ ln_b,
                                                short* __restrict__ cbn) {
  __shared__ __align__(16) short SL[32][40];   // masked S [t][s]
  __shared__ __align__(16) short PR[32][40];   // pr [t][p]
  __shared__ float CMB[32][260];
  __shared__ float scl[32], mu_s[32], rs_s[32];
  int tid = threadIdx.x;
  int bc = blockIdx.x;
  int lbase = bc * CL;
  int bb = bc >> 6, lloc = (bc & 63) * 32;
  if (tid < 32) scl[tid] = rsqrtf(fmaxf(sgc[lbase + tid], 1.f)) * INV_SQRT_P;
  // pr = (m1c*qc + m1s*qs)/sqrt(P), bf16 into PR[t][p]
#pragma unroll
  for (int it = 0; it < 2; ++it) {
    int i = it * 512 + tid;
    int p = i >> 5, t = i & 31;
    int gT = (bb * 32 + p) * L_ + lloc + t;
    int g = (lbase + t) * 32 + p;
    PR[t][p] = f2bf((m1cT[gT] * qc[g] + m1sT[gT] * qs[g]) * INV_SQRT_P);
  }
  int lane = tid & 63, w = tid >> 6;
  int ml = lane & 15, quad = lane >> 4, kq = quad * 8;
  int d0 = w * 32;
  floatx4 acc[2][2] = {};
  short8_t ka0 = *(const short8_t*)&K2bf[(lbase + ml) * 64 + kq];
  short8_t ka1 = *(const short8_t*)&K2bf[(lbase + 16 + ml) * 64 + kq];
  short8_t kb0 = *(const short8_t*)&K2bf[(lbase + ml) * 64 + 32 + kq];
  short8_t kb1 = *(const short8_t*)&K2bf[(lbase + 16 + ml) * 64 + 32 + kq];
  // Part 1, ks=0: K2[:,0:32] @ Uprev[0:32,:]  (B-frag from UT global)
#pragma unroll
  for (int nt = 0; nt < 2; ++nt) {
    short8_t b = *(const short8_t*)&UT[(bc * 256 + d0 + nt * 16 + ml) * 64 + kq];
    acc[0][nt] = __builtin_amdgcn_mfma_f32_16x16x32_bf16(ka0, b, acc[0][nt], 0, 0, 0);
    acc[1][nt] = __builtin_amdgcn_mfma_f32_16x16x32_bf16(ka1, b, acc[1][nt], 0, 0, 0);
  }
  // wave 0: S = K2 @ SP^T, mask, write SL[t][s]
  if (w == 0) {
    floatx4 sacc[2][2] = {};
#pragma unroll
    for (int ks2 = 0; ks2 < 2; ++ks2) {
      short8_t a0 = (ks2 == 0) ? ka0 : kb0;
      short8_t a1 = (ks2 == 0) ? ka1 : kb1;
      short8_t b0 = *(const short8_t*)&SPbf[(lbase + ml) * 64 + ks2 * 32 + kq];
      short8_t b1 = *(const short8_t*)&SPbf[(lbase + 16 + ml) * 64 + ks2 * 32 + kq];
      sacc[0][0] = __builtin_amdgcn_mfma_f32_16x16x32_bf16(a0, b0, sacc[0][0], 0, 0, 0);
      sacc[0][1] = __builtin_amdgcn_mfma_f32_16x16x32_bf16(a0, b1, sacc[0][1], 0, 0, 0);
      sacc[1][0] = __builtin_amdgcn_mfma_f32_16x16x32_bf16(a1, b0, sacc[1][0], 0, 0, 0);
      sacc[1][1] = __builtin_amdgcn_mfma_f32_16x16x32_bf16(a1, b1, sacc[1][1], 0, 0, 0);
    }
#pragma unroll
    for (int mt = 0; mt < 2; ++mt)
#pragma unroll
      for (int nt = 0; nt < 2; ++nt)
#pragma unroll
        for (int r = 0; r < 4; ++r) {
          int trow = mt * 16 + quad * 4 + r;
          int scol = nt * 16 + ml;
          float v = (scol <= trow) ? sacc[mt][nt][r] : 0.f;
          SL[trow][scol] = f2bf(v);
        }
  }
  __syncthreads();
  // Part 1, ks=1: K2[:,32:64] @ Uprev[32:64,:]
#pragma unroll
  for (int nt = 0; nt < 2; ++nt) {
    short8_t b = *(const short8_t*)&UT[(bc * 256 + d0 + nt * 16 + ml) * 64 + 32 + kq];
    acc[0][nt] = __builtin_amdgcn_mfma_f32_16x16x32_bf16(kb0, b, acc[0][nt], 0, 0, 0);
    acc[1][nt] = __builtin_amdgcn_mfma_f32_16x16x32_bf16(kb1, b, acc[1][nt], 0, 0, 0);
  }
  // Part 2: S @ gv
  {
    short8_t a0 = *(short8_t*)&SL[ml][kq];
    short8_t a1 = *(short8_t*)&SL[16 + ml][kq];
#pragma unroll
    for (int nt = 0; nt < 2; ++nt) {
      short8_t b = *(const short8_t*)&gvT[(bc * 256 + d0 + nt * 16 + ml) * 32 + kq];
      acc[0][nt] = __builtin_amdgcn_mfma_f32_16x16x32_bf16(a0, b, acc[0][nt], 0, 0, 0);
      acc[1][nt] = __builtin_amdgcn_mfma_f32_16x16x32_bf16(a1, b, acc[1][nt], 0, 0, 0);
    }
  }
  // pos_out MFMA: PR[t][p] @ W1OT[d][p]^T, K=32
  floatx4 macc[2][2] = {};
  {
    short8_t a0 = *(short8_t*)&PR[ml][kq];
    short8_t a1 = *(short8_t*)&PR[16 + ml][kq];
#pragma unroll
    for (int nt = 0; nt < 2; ++nt) {
      short8_t b = *(const short8_t*)&W1OT[(d0 + nt * 16 + ml) * 32 + kq];
      macc[0][nt] = __builtin_amdgcn_mfma_f32_16x16x32_bf16(a0, b, macc[0][nt], 0, 0, 0);
      macc[1][nt] = __builtin_amdgcn_mfma_f32_16x16x32_bf16(a1, b, macc[1][nt], 0, 0, 0);
    }
  }
#pragma unroll
  for (int mt = 0; mt < 2; ++mt)
#pragma unroll
    for (int nt = 0; nt < 2; ++nt) {
      int d = d0 + nt * 16 + ml;
      float bm = b_mem1o[d];
#pragma unroll
      for (int r = 0; r < 4; ++r) {
        int t = mt * 16 + quad * 4 + r;
        CMB[t][d] = acc[mt][nt][r] * scl[t] + macc[mt][nt][r] + bm;
      }
    }
  __syncthreads();
  {
    int t = tid >> 4, g = tid & 15;
    float s = 0.f, s2 = 0.f;
#pragma unroll
    for (int j = 0; j < 16; ++j) {
      float v = CMB[t][g + j * 16];
      s += v;
      s2 += v * v;
    }
#pragma unroll
    for (int m = 1; m < 16; m <<= 1) {
      s += __shfl_xor(s, m, 64);
      s2 += __shfl_xor(s2, m, 64);
    }
    if (g == 0) {
      float mu = s / (float)D_;
      float var = s2 / (float)D_ - mu * mu;
      mu_s[t] = mu;
      rs_s[t] = rsqrtf(var + 1e-5f);
    }
  }
  __syncthreads();
  {
    int d = tid & 255, th = tid >> 8;
    float lg = ln_g[d], lb = ln_b[d];
#pragma unroll
    for (int i = 0; i < 16; ++i) {
      int t = th * 16 + i;
      cbn[(lbase + t) * 256 + d] = f2bf((CMB[t][d] - mu_s[t]) * rs_s[t] * lg + lb);
    }
  }
}

extern "C" void kernel_launch(void* const* d_in, const int* in_sizes, int n_in,
                              void* d_out, int out_size, void* d_ws, size_t ws_size,
                              hipStream_t stream) {
  const float* x = (const float*)d_in[0];
  const float* pos = (const float*)d_in[1];
  const float* w_mem1v = (const float*)d_in[2];
  const float* b_mem1v = (const float*)d_in[3];
  const float* w_mem1o = (const float*)d_in[4];
  const float* b_mem1o = (const float*)d_in[5];
  const float* w_off = (const float*)d_in[6];
  const float* b_off = (const float*)d_in[7];
  const float* w_key = (const float*)d_in[8];
  const float* b_key = (const float*)d_in[9];
  const float* w_val = (const float*)d_in[10];
  const float* b_val = (const float*)d_in[11];
  const float* w_sk1 = (const float*)d_in[12];
  const float* b_sk1 = (const float*)d_in[13];
  const float* w_sk2 = (const float*)d_in[14];
  const float* b_sk2 = (const float*)d_in[15];
  const float* w_gate = (const float*)d_in[16];
  const float* b_gate = (const float*)d_in[17];
  const float* ln_g = (const float*)d_in[18];
  const float* ln_b = (const float*)d_in[19];
  const float* w_out = (const float*)d_in[20];
  const float* b_out = (const float*)d_in[21];
  float* out = (float*)d_out;
  float* ws = (float*)d_ws;

  const int BLP = B_ * L_ * P_;  // 262144
  const int BLD = B_ * L_ * D_;  // 2097152
  float* m1cT = ws;
  float* m1sT = m1cT + BLP;
  float* qc = m1sT + BLP;
  float* qs = qc + BLP;
  float* sg = qs + BLP;
  float* poff = sg + B_ * L_;
  float* ctxsum = poff + L_ * P_;              // B*64*256 = 65536 floats
  short* UT = (short*)(ctxsum + B_ * 64 * 256);
  short* xbf = UT + (size_t)B_ * NC * 256 * 64;
  short* cbn = xbf;                   // aliases xbf (dead after gemm2)
  short* ctxbf = xbf + BLD;
  short* hs = ctxbf + BLD;
  short* gvT = hs + BLD;
  short* K2bf = gvT + BLD;            // B*L*64
  short* SPbf = K2bf + B_ * L_ * 64;  // B*L*64
  short* WA = SPbf + B_ * L_ * 64;
  short* W1 = WA + 384 * 256;
  short* WO = W1 + 256 * 512;
  short* W2T = WO + 256 * 256;
  short* W1OT = W2T + 32 * 256;

  wprep<<<3776, 256, 0, stream>>>(x, pos, w_val, w_mem1v, w_off, b_off, w_key, w_gate,
                                  w_sk1, w_out, w_sk2, w_mem1o, WA, W1, WO, W2T, W1OT,
                                  xbf, poff, ctxsum);
  gemmA3<<<256, 384, 0, stream>>>(xbf, WA, pos, poff, b_mem1v, b_key, b_gate, b_val,
                                  m1cT, m1sT, qc, qs, K2bf, gvT, sg);
  scan_all<<<516, 256, 0, stream>>>(m1cT, m1sT, sg, x, ctxsum, ctxbf);
  gemm_k<4, 4, 1><<<128 * 4, 256, 0, stream>>>(xbf, ctxbf, W1, b_sk1, nullptr, nullptr, hs);
  kernelCD<<<(B_ * L_) / 32, 256, 0, stream>>>(hs, W2T, b_sk2, gvT, SPbf, UT);
  kernelE<<<256, 256, 0, stream>>>(UT);
  kernelFG<<<B_ * NC, 512, 0, stream>>>(UT, SPbf, K2bf, gvT, sg, m1cT, m1sT, qc, qs,
                                        W1OT, b_mem1o, ln_g, ln_b, cbn);
  gemm_k<2, 4, 2><<<128 * 4, 256, 0, stream>>>(cbn, nullptr, WO, b_out, x, out, nullptr);
}

// Round 3
// 171.459 us; speedup vs baseline: 1.0945x; 1.0515x over previous
//
#include <hip/hip_runtime.h>
#include <hip/hip_bf16.h>

constexpr int B_ = 4;
constexpr int L_ = 2048;
constexpr int D_ = 256;
constexpr int P_ = 32;
constexpr int CL = 32;   // chunk length for KV scan
constexpr int NC = L_ / CL;  // 64 chunks

#define PI_F 3.14159265358979323846f
#define INV_SQRT_P 0.17677669529663687f  // 1/sqrt(32)

typedef __attribute__((ext_vector_type(8))) short short8_t;
typedef __attribute__((ext_vector_type(4))) float floatx4;

static __device__ inline short f2bf(float f) {
  unsigned int u;
  __builtin_memcpy(&u, &f, 4);
  unsigned int r = (u + 0x7fffu + ((u >> 16) & 1u)) >> 16;
  return (short)r;
}
static __device__ inline float bf2f(short s) {
  unsigned int u = ((unsigned int)(unsigned short)s) << 16;
  float f;
  __builtin_memcpy(&f, &u, 4);
  return f;
}

// ---------------- wprep: weight casts/transposes + x->bf16 + poff + ctxsum -
__global__ void wprep(const float* __restrict__ x, const float* __restrict__ pos,
                      const float* __restrict__ w_val, const float* __restrict__ w_mem1v,
                      const float* __restrict__ w_off, const float* __restrict__ b_off,
                      const float* __restrict__ w_key, const float* __restrict__ w_gate,
                      const float* __restrict__ w_sk1, const float* __restrict__ w_out,
                      const float* __restrict__ w_sk2, const float* __restrict__ w_mem1o,
                      short* __restrict__ WA, short* __restrict__ W1,
                      short* __restrict__ WO, short* __restrict__ W2T,
                      short* __restrict__ W1OT,
                      short* __restrict__ xbf, float* __restrict__ poff,
                      float* __restrict__ ctxsum) {
  int blk = blockIdx.x, tid = threadIdx.x;
  if (blk < 384) {
    int idx = blk * 256 + tid;
    int n = idx >> 8, k = idx & 255;
    float v;
    if (n < 256) v = w_val[k * 256 + n];
    else if (n < 288) v = w_mem1v[k * 32 + (n - 256)];
    else if (n < 320) v = w_off[k * 32 + (n - 288)];
    else if (n < 352) v = w_key[k * 32 + (n - 320)];
    else if (n == 352) v = w_gate[k];
    else v = 0.f;
    WA[idx] = f2bf(v);
  } else if (blk < 896) {
    int idx = (blk - 384) * 256 + tid;
    int n = idx >> 9, k = idx & 511;
    W1[idx] = f2bf(w_sk1[k * 256 + n]);
  } else if (blk < 1152) {
    int idx = (blk - 896) * 256 + tid;
    int n = idx >> 8, k = idx & 255;
    WO[idx] = f2bf(w_out[k * 256 + n]);
  } else if (blk < 1184) {
    int idx = (blk - 1152) * 256 + tid;  // p*256 + k
    int p = idx >> 8, k = idx & 255;
    W2T[idx] = f2bf(w_sk2[k * 32 + p]);
  } else if (blk < 1216) {
    int idx = (blk - 1184) * 256 + tid;  // d*32 + p
    int d = idx >> 5, p = idx & 31;
    W1OT[idx] = f2bf(w_mem1o[p * 256 + d]);
  } else if (blk < 3264) {
    int idx = ((blk - 1216) * 256 + tid) * 4;
    float4 v = *(const float4*)&x[idx];
    short4 o;
    o.x = f2bf(v.x); o.y = f2bf(v.y); o.z = f2bf(v.z); o.w = f2bf(v.w);
    *(short4*)&xbf[idx] = o;
  } else if (blk < 3520) {
    int idx = (blk - 3264) * 256 + tid;
    int l = idx >> 5, p = idx & 31;
    float a = b_off[p];
#pragma unroll 8
    for (int j = 0; j < 32; ++j) a += pos[l * 32 + j] * w_off[(256 + j) * 32 + p];
    poff[idx] = a;
  } else {
    // ctx chunk sums: depends only on x
    int c2 = blk - 3520;
    int b = c2 >> 6, ch = c2 & 63;
    int xb = (b * L_ + ch * 32) * 256 + tid;
    float s = 0.f;
#pragma unroll 8
    for (int i = 0; i < 32; ++i) s += x[xb + i * 256];
    ctxsum[c2 * 256 + tid] = s;
  }
}

// ---------------- gemm32: bf16 MFMA GEMM, 32x64 tile, 4 waves --------------
// High-occupancy variant: 1024 blocks -> 4 blocks/CU -> 4 waves/SIMD.
// MODE 1: hs bf16 = gelu(A @ W + bias)
// MODE 2: out fp32 = xres + A0 @ W + bias
template <int KTILES, int MODE>
__global__ __launch_bounds__(256, 4) void gemm32(const short* __restrict__ A0,
                                                 const short* __restrict__ A1,
                                                 const short* __restrict__ W,
                                                 const float* __restrict__ bias,
                                                 const float* __restrict__ xres,
                                                 float* __restrict__ outf,
                                                 short* __restrict__ outb) {
  __shared__ short As[32][136];
  __shared__ short Bs[64][136];
  int tid = threadIdx.x;
  int mg = blockIdx.x >> 2, ng = blockIdx.x & 3;
  int tok0 = mg * 32, n0 = ng * 64;
  int lane = tid & 63, w = tid >> 6;
  int nw = w * 16;
  floatx4 acc[2] = {{0.f, 0.f, 0.f, 0.f}, {0.f, 0.f, 0.f, 0.f}};
  int r2 = tid >> 4, c8 = tid & 15;
  int ml = lane & 15, quad = lane >> 4, kq = quad * 8;
  const int K = KTILES * 128;

  for (int kt = 0; kt < KTILES; ++kt) {
    const short* Asrc;
    int cb;
    if (KTILES == 4) {
      Asrc = (kt < 2) ? A0 : A1;
      cb = (kt & 1) * 128;
    } else {
      Asrc = A0;
      cb = kt * 128;
    }
#pragma unroll
    for (int pass = 0; pass < 2; ++pass) {
      int row = pass * 16 + r2;
      *(short8_t*)&As[row][c8 * 8] =
          *(const short8_t*)&Asrc[(tok0 + row) * 256 + cb + c8 * 8];
    }
#pragma unroll
    for (int pass = 0; pass < 4; ++pass) {
      int row = pass * 16 + r2;
      *(short8_t*)&Bs[row][c8 * 8] =
          *(const short8_t*)&W[(n0 + row) * K + kt * 128 + c8 * 8];
    }
    __syncthreads();
#pragma unroll
    for (int s = 0; s < 4; ++s) {
      short8_t a0 = *(short8_t*)&As[ml][s * 32 + kq];
      short8_t a1 = *(short8_t*)&As[16 + ml][s * 32 + kq];
      short8_t b0 = *(short8_t*)&Bs[nw + ml][s * 32 + kq];
      acc[0] = __builtin_amdgcn_mfma_f32_16x16x32_bf16(a0, b0, acc[0], 0, 0, 0);
      acc[1] = __builtin_amdgcn_mfma_f32_16x16x32_bf16(a1, b0, acc[1], 0, 0, 0);
    }
    __syncthreads();
  }
  int n = n0 + nw + ml;
  float bv = bias ? bias[n] : 0.f;
#pragma unroll
  for (int mt = 0; mt < 2; ++mt) {
#pragma unroll
    for (int rg = 0; rg < 4; ++rg) {
      int tok = tok0 + mt * 16 + quad * 4 + rg;
      float v = acc[mt][rg] + bv;
      if (MODE == 1) {
        float g = 0.5f * v * (1.f + erff(v * 0.70710678118654752f));
        outb[tok * 256 + n] = f2bf(g);
      } else {
        outf[tok * 256 + n] = xres[tok * 256 + n] + v;
      }
    }
  }
}

// ---------------- gemmA3: fused gemm1 (Y = xbf@WA) + kernelA3 epilogue -----
// 512 blocks x 16-token chunks (384 threads, 6 waves) -> 3 waves/SIMD.
__global__ __launch_bounds__(384, 3) void gemmA3(const short* __restrict__ xbf,
                                                 const short* __restrict__ WA,
                                                 const float* __restrict__ pos,
                                                 const float* __restrict__ poff,
                                                 const float* __restrict__ b_mem1v,
                                                 const float* __restrict__ b_key,
                                                 const float* __restrict__ b_gate,
                                                 const float* __restrict__ b_val,
                                                 float* __restrict__ m1cT,
                                                 float* __restrict__ m1sT,
                                                 float* __restrict__ qc,
                                                 float* __restrict__ qs,
                                                 short* __restrict__ K2bf,
                                                 short* __restrict__ gvT,
                                                 float* __restrict__ sg) {
  __shared__ float YL[16][132];  // cols 256..383 of Y, fp32
  __shared__ float gsh[16];
  int tid = threadIdx.x;
  int lane = tid & 63, w = tid >> 6;
  int ml = lane & 15, quad = lane >> 4, kq = quad * 8;
  int bc = blockIdx.x;           // 16-token chunk
  int bc32 = bc >> 1, half = bc & 1;
  int tok0 = bc * 16;
  floatx4 acc[4] = {};
  const short* A0p = &xbf[(tok0 + ml) * 256 + kq];
  const short* Bp = &WA[(w * 64 + ml) * 256 + kq];
#pragma unroll
  for (int ks = 0; ks < 8; ++ks) {
    short8_t a0 = *(const short8_t*)(A0p + ks * 32);
#pragma unroll
    for (int nt = 0; nt < 4; ++nt) {
      short8_t b = *(const short8_t*)(Bp + nt * 16 * 256 + ks * 32);
      acc[nt] = __builtin_amdgcn_mfma_f32_16x16x32_bf16(a0, b, acc[nt], 0, 0, 0);
    }
  }
  // waves 4,5 stage cols 256..383 into LDS (fp32, no bf16 round-trip)
  if (w >= 4) {
#pragma unroll
    for (int nt = 0; nt < 4; ++nt) {
      int col = (w - 4) * 64 + nt * 16 + ml;
#pragma unroll
      for (int r = 0; r < 4; ++r)
        YL[quad * 4 + r][col] = acc[nt][r];
    }
  }
  __syncthreads();
  // A3 elementwise phase: 16 tok x 32 p = 512 items on threads 0..255
  if (tid < 256) {
#pragma unroll
    for (int it = 0; it < 2; ++it) {
      int idx = it * 256 + tid;
      int t = idx >> 5, p = idx & 31;
      int tok = tok0 + t, l = tok & (L_ - 1);
      int b = tok >> 11;
      float v1 = YL[t][p] + b_mem1v[p];
      float ph = pos[l * 32 + p];
      float pc = cosf(ph), ps = sinf(ph);
      int idxT = (b * 32 + p) * L_ + l;
      m1cT[idxT] = pc * v1;
      m1sT[idxT] = ps * v1;
      float off = tanhf(YL[t][32 + p] + poff[l * 32 + p]) * PI_F;
      float oc = cosf(off), os = sinf(off);
      int gidx = tok * 32 + p;
      qc[gidx] = pc * oc - ps * os;
      qs[gidx] = ps * oc + pc * os;
      float kp = tanhf(YL[t][64 + p] + b_key[p]) * PI_F;
      K2bf[tok * 64 + p] = f2bf(cosf(kp));
      K2bf[tok * 64 + 32 + p] = f2bf(sinf(kp));
      if (p == 0) {
        float g = 1.f / (1.f + expf(-(YL[t][96] + b_gate[0])));
        sg[tok] = g;
        gsh[t] = g;
      }
    }
  }
  __syncthreads();
  // gvT = (values + b_val) * gate, [bc32][d][t32] with t-slot = half*16+t
  if (w < 4) {
#pragma unroll
    for (int nt = 0; nt < 4; ++nt) {
      int d = w * 64 + nt * 16 + ml;
      float bv = b_val[d];
      int t0 = quad * 4;
      short4 o;
      o.x = f2bf((acc[nt][0] + bv) * gsh[t0 + 0]);
      o.y = f2bf((acc[nt][1] + bv) * gsh[t0 + 1]);
      o.z = f2bf((acc[nt][2] + bv) * gsh[t0 + 2]);
      o.w = f2bf((acc[nt][3] + bv) * gsh[t0 + 3]);
      *(short4*)&gvT[(bc32 * 256 + d) * 32 + half * 16 + t0] = o;
    }
  }
}

// ---------------- scan_all: m1 scans + sg scan + ctx prefix ----------------
// blk<128: m1cT row; blk<256: m1sT row; blk<260: sg; blk>=260: ctx -> ctxbf.
__global__ void scan_all(float* __restrict__ m1cT, float* __restrict__ m1sT,
                         float* __restrict__ sg, const float* __restrict__ x,
                         const float* __restrict__ ctxsum, short* __restrict__ ctxbf) {
  int blk = blockIdx.x;
  int tid = threadIdx.x;
  if (blk >= 260) {
    // ctx: chunk prefix of ctxsum (unroll-8 batched loads) + local scan
    int c2 = blk - 260;
    int b = c2 >> 6, ch = c2 & 63;
    float run = 0.f;
    int sb = b * 64 * 256 + tid;
    int c = 0;
    for (; c + 8 <= ch; c += 8) {
      float t0 = ctxsum[sb + (c + 0) * 256];
      float t1 = ctxsum[sb + (c + 1) * 256];
      float t2 = ctxsum[sb + (c + 2) * 256];
      float t3 = ctxsum[sb + (c + 3) * 256];
      float t4 = ctxsum[sb + (c + 4) * 256];
      float t5 = ctxsum[sb + (c + 5) * 256];
      float t6 = ctxsum[sb + (c + 6) * 256];
      float t7 = ctxsum[sb + (c + 7) * 256];
      run += ((t0 + t1) + (t2 + t3)) + ((t4 + t5) + (t6 + t7));
    }
    for (; c < ch; ++c) run += ctxsum[sb + c * 256];
    int xb = (b * L_ + ch * 32) * 256 + tid;
#pragma unroll 8
    for (int i = 0; i < 32; ++i) {
      run += x[xb + i * 256];
      int l = ch * 32 + i;
      ctxbf[xb + i * 256] = f2bf(run / (float)(l + 1));
    }
    return;
  }
  int lane = tid & 63, wid = tid >> 6;
  __shared__ float wsum[4];
  float carry = 0.f;
  float* arr;
  int base;
  if (blk < 256) {
    arr = (blk < 128) ? m1cT : m1sT;
    base = (blk & 127) * L_;
  } else {
    arr = sg;
    base = (blk - 256) * L_;
  }
  float v[8];
#pragma unroll
  for (int i = 0; i < 8; ++i) v[i] = arr[base + i * 256 + tid];
#pragma unroll
  for (int i = 0; i < 8; ++i) {
    float vv = v[i];
#pragma unroll
    for (int off = 1; off < 64; off <<= 1) {
      float n = __shfl_up(vv, off, 64);
      if (lane >= off) vv += n;
    }
    if (lane == 63) wsum[wid] = vv;
    __syncthreads();
    float add = carry;
    for (int w = 0; w < wid; ++w) add += wsum[w];
    arr[base + i * 256 + tid] = vv + add;
    carry += wsum[0] + wsum[1] + wsum[2] + wsum[3];
    __syncthreads();
  }
}

// ---------------- Kernel CD: storage phases (MFMA) + per-chunk U sums ------
// 512 blocks: bc = blk>>1 (32-token chunk), dh = blk&1 (d-half).
// Phase 1 (both halves): SP for the chunk; dh==0 writes SPbf.
// Phase 2: wave w covers d in [dh*128 + w*32, +32); short4 UT stores.
__global__ __launch_bounds__(256, 2) void kernelCD(const short* __restrict__ hs,
                                                   const short* __restrict__ W2T,
                                                   const float* __restrict__ b_sk2,
                                                   const short* __restrict__ gvT,
                                                   short* __restrict__ SPbf,
                                                   short* __restrict__ UT) {
  __shared__ __align__(16) short SPL[64][40];
  int tid = threadIdx.x;
  int bc = blockIdx.x >> 1, dh = blockIdx.x & 1;
  int tok0 = bc * 32;
  int lane = tid & 63, w = tid >> 6;
  int ml = lane & 15, quad = lane >> 4, kq = quad * 8;
  int th = w & 1, ph = w >> 1;
  floatx4 pacc = {};
#pragma unroll
  for (int s = 0; s < 8; ++s) {
    short8_t a = *(const short8_t*)&hs[(tok0 + th * 16 + ml) * 256 + s * 32 + kq];
    short8_t b0 = *(const short8_t*)&W2T[(ph * 16 + ml) * 256 + s * 32 + kq];
    pacc = __builtin_amdgcn_mfma_f32_16x16x32_bf16(a, b0, pacc, 0, 0, 0);
  }
  {
    int p = ph * 16 + ml;
    float bs = b_sk2[p];
#pragma unroll
    for (int r = 0; r < 4; ++r) {
      int tl = th * 16 + quad * 4 + r;
      int tok = tok0 + tl;
      float sp = tanhf(pacc[r] + bs) * PI_F;
      short c = f2bf(cosf(sp)), s = f2bf(sinf(sp));
      SPL[p][tl] = c;
      SPL[32 + p][tl] = s;
      if (dh == 0) {
        SPbf[tok * 64 + p] = c;
        SPbf[tok * 64 + 32 + p] = s;
      }
    }
  }
  __syncthreads();
  short8_t a[4];
#pragma unroll
  for (int mt = 0; mt < 4; ++mt) a[mt] = *(short8_t*)&SPL[mt * 16 + ml][kq];
  floatx4 acc[4][2] = {};
#pragma unroll
  for (int nt = 0; nt < 2; ++nt) {
    int d = dh * 128 + w * 32 + nt * 16 + ml;
    short8_t b = *(const short8_t*)&gvT[(bc * 256 + d) * 32 + kq];
#pragma unroll
    for (int mt = 0; mt < 4; ++mt)
      acc[mt][nt] = __builtin_amdgcn_mfma_f32_16x16x32_bf16(a[mt], b, acc[mt][nt], 0, 0, 0);
  }
#pragma unroll
  for (int mt = 0; mt < 4; ++mt)
#pragma unroll
    for (int nt = 0; nt < 2; ++nt) {
      int d = dh * 128 + w * 32 + nt * 16 + ml;
      short4 o;
      o.x = f2bf(acc[mt][nt][0]);
      o.y = f2bf(acc[mt][nt][1]);
      o.z = f2bf(acc[mt][nt][2]);
      o.w = f2bf(acc[mt][nt][3]);
      *(short4*)&UT[(bc * 256 + d) * 64 + mt * 16 + quad * 4] = o;
    }
}

// ---------------- Kernel E: in-place exclusive prefix over chunks (bf16) ---
__global__ void kernelE(short* __restrict__ UT) {
  int tid = blockIdx.x * 256 + threadIdx.x;  // B*256d*64q = 65536
  int q = tid & 63;
  int d = (tid >> 6) & 255;
  int b = tid >> 14;
  int base = ((b * NC) * 256 + d) * 64 + q;
  const int cs = 256 * 64;
  short v[64];
#pragma unroll
  for (int c = 0; c < 64; ++c) v[c] = UT[base + c * cs];
  float run = 0.f;
#pragma unroll
  for (int c = 0; c < 64; ++c) {
    UT[base + c * cs] = f2bf(run);
    run += bf2f(v[c]);
  }
}

// ---------------- Kernel FG: retrieval + pos_out + LN -> cbn ---------------
// 512 threads / 8 waves: wave w owns d-columns [w*32, w*32+32).
__global__ __launch_bounds__(512, 2) void kernelFG(const short* __restrict__ UT,
                                                   const short* __restrict__ SPbf,
                                                   const short* __restrict__ K2bf,
                                                   const short* __restrict__ gvT,
                                                   const float* __restrict__ sgc,
                                                   const float* __restrict__ m1cT,
                                                   const float* __restrict__ m1sT,
                                                   const float* __restrict__ qc,
                                                   const float* __restrict__ qs,
                                                   const short* __restrict__ W1OT,
                                                   const float* __restrict__ b_mem1o,
                                                   const float* __restrict__ ln_g,
                                                   const float* __restrict__ ln_b,
                                                   short* __restrict__ cbn) {
  __shared__ __align__(16) short SL[32][40];   // masked S [t][s]
  __shared__ __align__(16) short PR[32][40];   // pr [t][p]
  __shared__ float CMB[32][260];
  __shared__ float scl[32], mu_s[32], rs_s[32];
  int tid = threadIdx.x;
  int bc = blockIdx.x;
  int lbase = bc * CL;
  int bb = bc >> 6, lloc = (bc & 63) * 32;
  if (tid < 32) scl[tid] = rsqrtf(fmaxf(sgc[lbase + tid], 1.f)) * INV_SQRT_P;
  // pr = (m1c*qc + m1s*qs)/sqrt(P), bf16 into PR[t][p]
#pragma unroll
  for (int it = 0; it < 2; ++it) {
    int i = it * 512 + tid;
    int p = i >> 5, t = i & 31;
    int gT = (bb * 32 + p) * L_ + lloc + t;
    int g = (lbase + t) * 32 + p;
    PR[t][p] = f2bf((m1cT[gT] * qc[g] + m1sT[gT] * qs[g]) * INV_SQRT_P);
  }
  int lane = tid & 63, w = tid >> 6;
  int ml = lane & 15, quad = lane >> 4, kq = quad * 8;
  int d0 = w * 32;
  floatx4 acc[2][2] = {};
  short8_t ka0 = *(const short8_t*)&K2bf[(lbase + ml) * 64 + kq];
  short8_t ka1 = *(const short8_t*)&K2bf[(lbase + 16 + ml) * 64 + kq];
  short8_t kb0 = *(const short8_t*)&K2bf[(lbase + ml) * 64 + 32 + kq];
  short8_t kb1 = *(const short8_t*)&K2bf[(lbase + 16 + ml) * 64 + 32 + kq];
  // Part 1, ks=0: K2[:,0:32] @ Uprev[0:32,:]  (B-frag from UT global)
#pragma unroll
  for (int nt = 0; nt < 2; ++nt) {
    short8_t b = *(const short8_t*)&UT[(bc * 256 + d0 + nt * 16 + ml) * 64 + kq];
    acc[0][nt] = __builtin_amdgcn_mfma_f32_16x16x32_bf16(ka0, b, acc[0][nt], 0, 0, 0);
    acc[1][nt] = __builtin_amdgcn_mfma_f32_16x16x32_bf16(ka1, b, acc[1][nt], 0, 0, 0);
  }
  // wave 0: S = K2 @ SP^T, mask, write SL[t][s]
  if (w == 0) {
    floatx4 sacc[2][2] = {};
#pragma unroll
    for (int ks2 = 0; ks2 < 2; ++ks2) {
      short8_t a0 = (ks2 == 0) ? ka0 : kb0;
      short8_t a1 = (ks2 == 0) ? ka1 : kb1;
      short8_t b0 = *(const short8_t*)&SPbf[(lbase + ml) * 64 + ks2 * 32 + kq];
      short8_t b1 = *(const short8_t*)&SPbf[(lbase + 16 + ml) * 64 + ks2 * 32 + kq];
      sacc[0][0] = __builtin_amdgcn_mfma_f32_16x16x32_bf16(a0, b0, sacc[0][0], 0, 0, 0);
      sacc[0][1] = __builtin_amdgcn_mfma_f32_16x16x32_bf16(a0, b1, sacc[0][1], 0, 0, 0);
      sacc[1][0] = __builtin_amdgcn_mfma_f32_16x16x32_bf16(a1, b0, sacc[1][0], 0, 0, 0);
      sacc[1][1] = __builtin_amdgcn_mfma_f32_16x16x32_bf16(a1, b1, sacc[1][1], 0, 0, 0);
    }
#pragma unroll
    for (int mt = 0; mt < 2; ++mt)
#pragma unroll
      for (int nt = 0; nt < 2; ++nt)
#pragma unroll
        for (int r = 0; r < 4; ++r) {
          int trow = mt * 16 + quad * 4 + r;
          int scol = nt * 16 + ml;
          float v = (scol <= trow) ? sacc[mt][nt][r] : 0.f;
          SL[trow][scol] = f2bf(v);
        }
  }
  __syncthreads();
  // Part 1, ks=1: K2[:,32:64] @ Uprev[32:64,:]
#pragma unroll
  for (int nt = 0; nt < 2; ++nt) {
    short8_t b = *(const short8_t*)&UT[(bc * 256 + d0 + nt * 16 + ml) * 64 + 32 + kq];
    acc[0][nt] = __builtin_amdgcn_mfma_f32_16x16x32_bf16(kb0, b, acc[0][nt], 0, 0, 0);
    acc[1][nt] = __builtin_amdgcn_mfma_f32_16x16x32_bf16(kb1, b, acc[1][nt], 0, 0, 0);
  }
  // Part 2: S @ gv
  {
    short8_t a0 = *(short8_t*)&SL[ml][kq];
    short8_t a1 = *(short8_t*)&SL[16 + ml][kq];
#pragma unroll
    for (int nt = 0; nt < 2; ++nt) {
      short8_t b = *(const short8_t*)&gvT[(bc * 256 + d0 + nt * 16 + ml) * 32 + kq];
      acc[0][nt] = __builtin_amdgcn_mfma_f32_16x16x32_bf16(a0, b, acc[0][nt], 0, 0, 0);
      acc[1][nt] = __builtin_amdgcn_mfma_f32_16x16x32_bf16(a1, b, acc[1][nt], 0, 0, 0);
    }
  }
  // pos_out MFMA: PR[t][p] @ W1OT[d][p]^T, K=32
  floatx4 macc[2][2] = {};
  {
    short8_t a0 = *(short8_t*)&PR[ml][kq];
    short8_t a1 = *(short8_t*)&PR[16 + ml][kq];
#pragma unroll
    for (int nt = 0; nt < 2; ++nt) {
      short8_t b = *(const short8_t*)&W1OT[(d0 + nt * 16 + ml) * 32 + kq];
      macc[0][nt] = __builtin_amdgcn_mfma_f32_16x16x32_bf16(a0, b, macc[0][nt], 0, 0, 0);
      macc[1][nt] = __builtin_amdgcn_mfma_f32_16x16x32_bf16(a1, b, macc[1][nt], 0, 0, 0);
    }
  }
#pragma unroll
  for (int mt = 0; mt < 2; ++mt)
#pragma unroll
    for (int nt = 0; nt < 2; ++nt) {
      int d = d0 + nt * 16 + ml;
      float bm = b_mem1o[d];
#pragma unroll
      for (int r = 0; r < 4; ++r) {
        int t = mt * 16 + quad * 4 + r;
        CMB[t][d] = acc[mt][nt][r] * scl[t] + macc[mt][nt][r] + bm;
      }
    }
  __syncthreads();
  {
    int t = tid >> 4, g = tid & 15;
    float s = 0.f, s2 = 0.f;
#pragma unroll
    for (int j = 0; j < 16; ++j) {
      float v = CMB[t][g + j * 16];
      s += v;
      s2 += v * v;
    }
#pragma unroll
    for (int m = 1; m < 16; m <<= 1) {
      s += __shfl_xor(s, m, 64);
      s2 += __shfl_xor(s2, m, 64);
    }
    if (g == 0) {
      float mu = s / (float)D_;
      float var = s2 / (float)D_ - mu * mu;
      mu_s[t] = mu;
      rs_s[t] = rsqrtf(var + 1e-5f);
    }
  }
  __syncthreads();
  {
    int d = tid & 255, th = tid >> 8;
    float lg = ln_g[d], lb = ln_b[d];
#pragma unroll
    for (int i = 0; i < 16; ++i) {
      int t = th * 16 + i;
      cbn[(lbase + t) * 256 + d] = f2bf((CMB[t][d] - mu_s[t]) * rs_s[t] * lg + lb);
    }
  }
}

extern "C" void kernel_launch(void* const* d_in, const int* in_sizes, int n_in,
                              void* d_out, int out_size, void* d_ws, size_t ws_size,
                              hipStream_t stream) {
  const float* x = (const float*)d_in[0];
  const float* pos = (const float*)d_in[1];
  const float* w_mem1v = (const float*)d_in[2];
  const float* b_mem1v = (const float*)d_in[3];
  const float* w_mem1o = (const float*)d_in[4];
  const float* b_mem1o = (const float*)d_in[5];
  const float* w_off = (const float*)d_in[6];
  const float* b_off = (const float*)d_in[7];
  const float* w_key = (const float*)d_in[8];
  const float* b_key = (const float*)d_in[9];
  const float* w_val = (const float*)d_in[10];
  const float* b_val = (const float*)d_in[11];
  const float* w_sk1 = (const float*)d_in[12];
  const float* b_sk1 = (const float*)d_in[13];
  const float* w_sk2 = (const float*)d_in[14];
  const float* b_sk2 = (const float*)d_in[15];
  const float* w_gate = (const float*)d_in[16];
  const float* b_gate = (const float*)d_in[17];
  const float* ln_g = (const float*)d_in[18];
  const float* ln_b = (const float*)d_in[19];
  const float* w_out = (const float*)d_in[20];
  const float* b_out = (const float*)d_in[21];
  float* out = (float*)d_out;
  float* ws = (float*)d_ws;

  const int BLP = B_ * L_ * P_;  // 262144
  const int BLD = B_ * L_ * D_;  // 2097152
  float* m1cT = ws;
  float* m1sT = m1cT + BLP;
  float* qc = m1sT + BLP;
  float* qs = qc + BLP;
  float* sg = qs + BLP;
  float* poff = sg + B_ * L_;
  float* ctxsum = poff + L_ * P_;              // B*64*256 = 65536 floats
  short* UT = (short*)(ctxsum + B_ * 64 * 256);
  short* xbf = UT + (size_t)B_ * NC * 256 * 64;
  short* cbn = xbf;                   // aliases xbf (dead after gemm2 input prep)
  short* ctxbf = xbf + BLD;
  short* hs = ctxbf + BLD;
  short* gvT = hs + BLD;
  short* K2bf = gvT + BLD;            // B*L*64
  short* SPbf = K2bf + B_ * L_ * 64;  // B*L*64
  short* WA = SPbf + B_ * L_ * 64;
  short* W1 = WA + 384 * 256;
  short* WO = W1 + 256 * 512;
  short* W2T = WO + 256 * 256;
  short* W1OT = W2T + 32 * 256;

  wprep<<<3776, 256, 0, stream>>>(x, pos, w_val, w_mem1v, w_off, b_off, w_key, w_gate,
                                  w_sk1, w_out, w_sk2, w_mem1o, WA, W1, WO, W2T, W1OT,
                                  xbf, poff, ctxsum);
  gemmA3<<<512, 384, 0, stream>>>(xbf, WA, pos, poff, b_mem1v, b_key, b_gate, b_val,
                                  m1cT, m1sT, qc, qs, K2bf, gvT, sg);
  scan_all<<<516, 256, 0, stream>>>(m1cT, m1sT, sg, x, ctxsum, ctxbf);
  gemm32<4, 1><<<256 * 4, 256, 0, stream>>>(xbf, ctxbf, W1, b_sk1, nullptr, nullptr, hs);
  kernelCD<<<512, 256, 0, stream>>>(hs, W2T, b_sk2, gvT, SPbf, UT);
  kernelE<<<256, 256, 0, stream>>>(UT);
  kernelFG<<<B_ * NC, 512, 0, stream>>>(UT, SPbf, K2bf, gvT, sg, m1cT, m1sT, qc, qs,
                                        W1OT, b_mem1o, ln_g, ln_b, cbn);
  gemm32<2, 2><<<256 * 4, 256, 0, stream>>>(cbn, nullptr, WO, b_out, x, out, nullptr);
}